// Round 1
// baseline (712.713 us; speedup 1.0000x reference)
//
#include <hip/hip_runtime.h>
#include <cmath>

namespace {
constexpr int Pn = 128;
constexpr int Hn = 512;
constexpr int Ln = 8192;
constexpr int BS = 8;
// ws float layout:
// [0,128)          Lambda_bar re
// [128,256)        Lambda_bar im
// [256, 256+131072)        Bmat [2P][H]  (rows 0..127 re, 128..255 im)
// [131328, 262400)         Cmat [H][2P]  (+2*C_re | -2*C_im)
// [262400, ...)            Bu   [NB][2P][L]
constexpr int HEAD = 256 + 2 * Pn * Hn + Hn * 2 * Pn; // 262400 floats
}

// ---------------------------------------------------------------- precompute
__global__ void precompute_kernel(const float* __restrict__ Lre,
                                  const float* __restrict__ Lim,
                                  const float* __restrict__ Bin,
                                  const float* __restrict__ Cin,
                                  const float* __restrict__ lstep,
                                  float* __restrict__ ws) {
  int tid = blockIdx.x * blockDim.x + threadIdx.x;
  if (tid < 2 * Pn * Hn) {
    // Bmat element: row r in [0,256), col h
    int r = tid >> 9;          // / 512
    int h = tid & (Hn - 1);
    int p = r & (Pn - 1);
    float st = expf(lstep[p]);
    float lr = Lre[p], li = Lim[p];
    float er = expf(lr * st);
    float cr = er * cosf(li * st);   // Lambda_bar re
    float ci = er * sinf(li * st);   // Lambda_bar im
    // w = (Lambda_bar - 1) / Lambda
    float nr = cr - 1.0f, ni = ci;
    float inv = 1.0f / (lr * lr + li * li);
    float wr = (nr * lr + ni * li) * inv;
    float wi = (ni * lr - nr * li) * inv;
    float btr = Bin[(p * Hn + h) * 2 + 0];
    float bti = Bin[(p * Hn + h) * 2 + 1];
    float val = (r < Pn) ? (wr * btr - wi * bti) : (wr * bti + wi * btr);
    ws[256 + tid] = val;
  } else if (tid < 2 * Pn * Hn + Hn * 2 * Pn) {
    int j = tid - 2 * Pn * Hn;
    int h = j >> 8;            // / 256
    int c = j & 255;
    int p = c & (Pn - 1);
    float v = (c < Pn) ? 2.0f * Cin[(h * Pn + p) * 2 + 0]
                       : -2.0f * Cin[(h * Pn + p) * 2 + 1];
    ws[256 + 2 * Pn * Hn + j] = v;
  } else if (tid < HEAD) {
    int j = tid - (2 * Pn * Hn + Hn * 2 * Pn);
    int p = j & (Pn - 1);
    float st = expf(lstep[p]);
    float lr = Lre[p], li = Lim[p];
    float er = expf(lr * st);
    ws[j] = (j < Pn) ? er * cosf(li * st) : er * sinf(li * st);
  }
}

// ---------------------------------------------------------------- GEMM1
// Bu[bz][2P][L] = Bmat[2P][H] @ U[(b0+bz)][H][L]
__global__ __launch_bounds__(256) void gemm1_kernel(
    const float* __restrict__ Amat,   // [256][512]
    const float* __restrict__ U,      // [8][512][8192]
    float* __restrict__ Bu,           // [NB][256][8192]
    int b0) {
  constexpr int TM = 64, TN = 64, TK = 16;
  __shared__ float As[TK][TM + 4];   // stored transposed: As[k][m]
  __shared__ float Bs[TK][TN];
  const int t = threadIdx.x;
  const int n0 = blockIdx.x * TN;
  const int m0 = blockIdx.y * TM;
  const int bz = blockIdx.z;
  const float* Ub = U + (size_t)(b0 + bz) * Hn * Ln;

  const int tm4 = (t >> 4) * 4, tn4 = (t & 15) * 4;
  const int la_r = t >> 4, la_c = t & 15;   // A loader: 16 rows x 16 cols per pass
  const int lb_r = t >> 6, lb_c = t & 63;   // B loader: 4 rows x 64 cols per pass

  float acc[4][4] = {};
  for (int k0 = 0; k0 < Hn; k0 += TK) {
#pragma unroll
    for (int i = 0; i < 4; i++)
      As[la_c][la_r + 16 * i] = Amat[(m0 + la_r + 16 * i) * Hn + k0 + la_c];
#pragma unroll
    for (int i = 0; i < 4; i++)
      Bs[lb_r + 4 * i][lb_c] =
          Ub[(size_t)(k0 + lb_r + 4 * i) * Ln + n0 + lb_c];
    __syncthreads();
#pragma unroll
    for (int k = 0; k < TK; k++) {
      const float4 a = *(const float4*)&As[k][tm4];
      const float4 b = *(const float4*)&Bs[k][tn4];
      float av[4] = {a.x, a.y, a.z, a.w};
      float bv[4] = {b.x, b.y, b.z, b.w};
#pragma unroll
      for (int i = 0; i < 4; i++)
#pragma unroll
        for (int j = 0; j < 4; j++)
          acc[i][j] = fmaf(av[i], bv[j], acc[i][j]);
    }
    __syncthreads();
  }
#pragma unroll
  for (int i = 0; i < 4; i++) {
    float4 v = make_float4(acc[i][0], acc[i][1], acc[i][2], acc[i][3]);
    *(float4*)&Bu[((size_t)bz * 256 + m0 + tm4 + i) * Ln + n0 + tn4] = v;
  }
}

// ---------------------------------------------------------------- scan
// in-place over Bu: x[l] = Lbar * x[l-1] + Bu[l], per (bz, p)
__global__ __launch_bounds__(256) void scan_kernel(float* __restrict__ Bu,
                                                   const float* __restrict__ ws) {
  const int p = blockIdx.x;
  const int bz = blockIdx.y;
  const float Ar = ws[p], Ai = ws[Pn + p];
  float* rre = Bu + ((size_t)bz * 256 + p) * Ln;
  float* rim = Bu + ((size_t)bz * 256 + Pn + p) * Ln;
  const int t = threadIdx.x;
  const int l0 = t * 32;

  float br[32], bi[32];
  const float4* pr = (const float4*)(rre + l0);
  const float4* pi = (const float4*)(rim + l0);
#pragma unroll
  for (int i = 0; i < 8; i++) {
    float4 v = pr[i];
    br[4 * i] = v.x; br[4 * i + 1] = v.y; br[4 * i + 2] = v.z; br[4 * i + 3] = v.w;
  }
#pragma unroll
  for (int i = 0; i < 8; i++) {
    float4 v = pi[i];
    bi[4 * i] = v.x; bi[4 * i + 1] = v.y; bi[4 * i + 2] = v.z; bi[4 * i + 3] = v.w;
  }

  float xr = 0.f, xi = 0.f;
#pragma unroll
  for (int j = 0; j < 32; j++) {
    float nr = fmaf(Ar, xr, fmaf(-Ai, xi, br[j]));
    float ni = fmaf(Ar, xi, fmaf(Ai, xr, bi[j]));
    xr = nr; xi = ni;
  }
  // A^32 by repeated squaring
  float ar = Ar, ai = Ai;
#pragma unroll
  for (int s = 0; s < 5; s++) {
    float trr = ar * ar - ai * ai;
    float tii = 2.0f * ar * ai;
    ar = trr; ai = tii;
  }

  __shared__ float sar[256], sai[256], sbr[256], sbi[256];
  sar[t] = ar; sai[t] = ai; sbr[t] = xr; sbi[t] = xi;
  for (int off = 1; off < 256; off <<= 1) {
    __syncthreads();
    float par = 0.f, pai = 0.f, pbr = 0.f, pbi = 0.f;
    float car = 0.f, cai = 0.f, cbr = 0.f, cbi = 0.f;
    if (t >= off) {
      par = sar[t - off]; pai = sai[t - off];
      pbr = sbr[t - off]; pbi = sbi[t - off];
      car = sar[t]; cai = sai[t]; cbr = sbr[t]; cbi = sbi[t];
    }
    __syncthreads();
    if (t >= off) {
      sbr[t] = cbr + car * pbr - cai * pbi;
      sbi[t] = cbi + car * pbi + cai * pbr;
      sar[t] = car * par - cai * pai;
      sai[t] = car * pai + cai * par;
    }
  }
  __syncthreads();
  float cr = (t > 0) ? sbr[t - 1] : 0.f;
  float ci = (t > 0) ? sbi[t - 1] : 0.f;

  xr = cr; xi = ci;
  float4* qr = (float4*)(rre + l0);
  float4* qi = (float4*)(rim + l0);
#pragma unroll
  for (int i = 0; i < 8; i++) {
    float4 vr, vi;
#pragma unroll
    for (int c = 0; c < 4; c++) {
      float nr = fmaf(Ar, xr, fmaf(-Ai, xi, br[4 * i + c]));
      float ni = fmaf(Ar, xi, fmaf(Ai, xr, bi[4 * i + c]));
      xr = nr; xi = ni;
      (&vr.x)[c] = xr;
      (&vi.x)[c] = xi;
    }
    qr[i] = vr;
    qi[i] = vi;
  }
}

// ---------------------------------------------------------------- GEMM2 + epilogue
// Out[(b0+bz)][H][L] = gelu( Cmat[H][2P] @ Xs[bz][2P][L] + D[h]*U[b][h][l] )
__global__ __launch_bounds__(256) void gemm2_kernel(
    const float* __restrict__ Cmat,   // [512][256]
    const float* __restrict__ Xs,     // [NB][256][8192]
    const float* __restrict__ U,      // [8][512][8192]
    const float* __restrict__ Dv,     // [512]
    float* __restrict__ Out,          // [8][512][8192]
    int b0) {
  constexpr int TM = 64, TN = 64, TK = 16;
  __shared__ float As[TK][TM + 4];
  __shared__ float Bs[TK][TN];
  const int t = threadIdx.x;
  const int n0 = blockIdx.x * TN;
  const int m0 = blockIdx.y * TM;
  const int bz = blockIdx.z;
  const int b = b0 + bz;

  const int tm4 = (t >> 4) * 4, tn4 = (t & 15) * 4;
  const int la_r = t >> 4, la_c = t & 15;
  const int lb_r = t >> 6, lb_c = t & 63;

  float acc[4][4] = {};
  for (int k0 = 0; k0 < 2 * Pn; k0 += TK) {
#pragma unroll
    for (int i = 0; i < 4; i++)
      As[la_c][la_r + 16 * i] = Cmat[(m0 + la_r + 16 * i) * (2 * Pn) + k0 + la_c];
#pragma unroll
    for (int i = 0; i < 4; i++)
      Bs[lb_r + 4 * i][lb_c] =
          Xs[((size_t)bz * 256 + k0 + lb_r + 4 * i) * Ln + n0 + lb_c];
    __syncthreads();
#pragma unroll
    for (int k = 0; k < TK; k++) {
      const float4 a = *(const float4*)&As[k][tm4];
      const float4 b2 = *(const float4*)&Bs[k][tn4];
      float av[4] = {a.x, a.y, a.z, a.w};
      float bv[4] = {b2.x, b2.y, b2.z, b2.w};
#pragma unroll
      for (int i = 0; i < 4; i++)
#pragma unroll
        for (int j = 0; j < 4; j++)
          acc[i][j] = fmaf(av[i], bv[j], acc[i][j]);
    }
    __syncthreads();
  }
#pragma unroll
  for (int i = 0; i < 4; i++) {
    int h = m0 + tm4 + i;
    float dh = Dv[h];
    const float4 uv = *(const float4*)&U[((size_t)b * Hn + h) * Ln + n0 + tn4];
    float y[4] = {acc[i][0] + dh * uv.x, acc[i][1] + dh * uv.y,
                  acc[i][2] + dh * uv.z, acc[i][3] + dh * uv.w};
    float4 o;
#pragma unroll
    for (int j = 0; j < 4; j++)
      (&o.x)[j] = 0.5f * y[j] * (1.0f + erff(y[j] * 0.70710678118654752f));
    *(float4*)&Out[((size_t)b * Hn + h) * Ln + n0 + tn4] = o;
  }
}

// ---------------------------------------------------------------- launch
extern "C" void kernel_launch(void* const* d_in, const int* in_sizes, int n_in,
                              void* d_out, int out_size, void* d_ws, size_t ws_size,
                              hipStream_t stream) {
  const float* U   = (const float*)d_in[0];
  const float* Lre = (const float*)d_in[1];
  const float* Lim = (const float*)d_in[2];
  const float* Bin = (const float*)d_in[3];
  const float* Cin = (const float*)d_in[4];
  const float* Dv  = (const float*)d_in[5];
  const float* ls  = (const float*)d_in[6];
  float* out = (float*)d_out;
  float* ws  = (float*)d_ws;

  precompute_kernel<<<(HEAD + 255) / 256, 256, 0, stream>>>(Lre, Lim, Bin, Cin, ls, ws);

  // batch chunking if workspace is small (deterministic per session)
  int NB = 8;
  while (NB > 1 &&
         ws_size < ((size_t)HEAD + (size_t)NB * 2 * Pn * Ln) * sizeof(float))
    NB >>= 1;
  float* Bu = ws + HEAD;

  for (int b0 = 0; b0 < BS; b0 += NB) {
    gemm1_kernel<<<dim3(Ln / 64, 256 / 64, NB), 256, 0, stream>>>(ws + 256, U, Bu, b0);
    scan_kernel<<<dim3(Pn, NB), 256, 0, stream>>>(Bu, ws);
    gemm2_kernel<<<dim3(Ln / 64, Hn / 64, NB), 256, 0, stream>>>(
        ws + 256 + 2 * Pn * Hn, Bu, U, Dv, out, b0);
  }
}

// Round 2
// 462.359 us; speedup vs baseline: 1.5415x; 1.5415x over previous
//
#include <hip/hip_runtime.h>
#include <hip/hip_bf16.h>
#include <cmath>

namespace {
constexpr int Pn = 128;
constexpr int Hn = 512;
constexpr int Ln = 8192;
constexpr int BS = 8;
// ws byte layout:
//   [0,1024)              Lambda_bar fp32 (re[128] | im[128])
//   [1024, 263168)        Bmat bf16 [256][512]  (rows 0..127 re, 128..255 im)
//   [263168, 525312)      Cmat bf16 [512][256]  (+2*C_re | -2*C_im)
//   [525312, ...)         Ut bf16 [NB][8192][512] ; Bu fp32 [NB][256][8192] ;
//                         Xst bf16 [NB][8192][256]
constexpr size_t HEADB = 525312;
constexpr size_t SZ_UT = (size_t)Ln * Hn * 2;      // 8388608 per batch
constexpr size_t SZ_BU = (size_t)256 * Ln * 4;     // 8388608 per batch
constexpr size_t SZ_XS = (size_t)Ln * 256 * 2;     // 4194304 per batch
}

typedef __attribute__((ext_vector_type(4))) float f32x4;
typedef __attribute__((ext_vector_type(8))) short bf16x8;
typedef __attribute__((ext_vector_type(4))) short short4v;

static __device__ inline short f2bf(float x) {
  __hip_bfloat16 h = __float2bfloat16(x);
  return *(short*)&h;
}

static __device__ inline void async_copy16(const void* g, void* l) {
  __builtin_amdgcn_global_load_lds(
      (const __attribute__((address_space(1))) unsigned int*)g,
      (__attribute__((address_space(3))) unsigned int*)l, 16, 0, 0);
}

// ---------------------------------------------------------------- precompute
__global__ void precompute_kernel(const float* __restrict__ Lre,
                                  const float* __restrict__ Lim,
                                  const float* __restrict__ Bin,
                                  const float* __restrict__ Cin,
                                  const float* __restrict__ lstep,
                                  float* __restrict__ Lam,
                                  __hip_bfloat16* __restrict__ Bmat,
                                  __hip_bfloat16* __restrict__ Cmat) {
  int tid = blockIdx.x * blockDim.x + threadIdx.x;
  if (tid < 2 * Pn * Hn) {
    int r = tid >> 9;          // row in [0,256)
    int h = tid & (Hn - 1);
    int p = r & (Pn - 1);
    float st = expf(lstep[p]);
    float lr = Lre[p], li = Lim[p];
    float er = expf(lr * st);
    float cr = er * cosf(li * st);
    float ci = er * sinf(li * st);
    float nr = cr - 1.0f, ni = ci;
    float inv = 1.0f / (lr * lr + li * li);
    float wr = (nr * lr + ni * li) * inv;
    float wi = (ni * lr - nr * li) * inv;
    float btr = Bin[(p * Hn + h) * 2 + 0];
    float bti = Bin[(p * Hn + h) * 2 + 1];
    float val = (r < Pn) ? (wr * btr - wi * bti) : (wr * bti + wi * btr);
    Bmat[tid] = __float2bfloat16(val);
  } else if (tid < 4 * Pn * Hn) {
    int j = tid - 2 * Pn * Hn;
    int h = j >> 8;
    int c = j & 255;
    int p = c & (Pn - 1);
    float v = (c < Pn) ? 2.0f * Cin[(h * Pn + p) * 2 + 0]
                       : -2.0f * Cin[(h * Pn + p) * 2 + 1];
    Cmat[j] = __float2bfloat16(v);
  } else if (tid < 4 * Pn * Hn + 256) {
    int j = tid - 4 * Pn * Hn;
    int p = j & (Pn - 1);
    float st = expf(lstep[p]);
    float lr = Lre[p], li = Lim[p];
    float er = expf(lr * st);
    Lam[j] = (j < Pn) ? er * cosf(li * st) : er * sinf(li * st);
  }
}

// ---------------------------------------------------------------- cvt_u
// U fp32 [b][H][L] -> Ut bf16 [bz][L][H]
__global__ __launch_bounds__(256) void cvt_u_kernel(
    const float* __restrict__ U, __hip_bfloat16* __restrict__ Ut, int b0) {
  __shared__ float tile[64][65];
  const int l0 = blockIdx.x * 64, h0 = blockIdx.y * 64, bz = blockIdx.z;
  const float* Ub = U + (size_t)(b0 + bz) * Hn * Ln;
  __hip_bfloat16* Utb = Ut + (size_t)bz * Ln * Hn;
  const int t = threadIdx.x;
  const int tr = t >> 4, tc = t & 15;
#pragma unroll
  for (int i = 0; i < 4; i++) {
    float4 v = *(const float4*)&Ub[(size_t)(h0 + tr + 16 * i) * Ln + l0 + tc * 4];
    tile[tr + 16 * i][tc * 4 + 0] = v.x;
    tile[tr + 16 * i][tc * 4 + 1] = v.y;
    tile[tr + 16 * i][tc * 4 + 2] = v.z;
    tile[tr + 16 * i][tc * 4 + 3] = v.w;
  }
  __syncthreads();
#pragma unroll
  for (int i = 0; i < 4; i++) {
    int l = tr + 16 * i;
    short4v o;
    o.x = f2bf(tile[tc * 4 + 0][l]);
    o.y = f2bf(tile[tc * 4 + 1][l]);
    o.z = f2bf(tile[tc * 4 + 2][l]);
    o.w = f2bf(tile[tc * 4 + 3][l]);
    *(short4v*)&Utb[(size_t)(l0 + l) * Hn + h0 + tc * 4] = o;
  }
}

// ---------------------------------------------------------------- cvt_xs
// Bu fp32 [bz][256][L] -> Xst bf16 [bz][L][256]
__global__ __launch_bounds__(256) void cvt_xs_kernel(
    const float* __restrict__ Bu, __hip_bfloat16* __restrict__ Xst) {
  __shared__ float tile[64][65];
  const int l0 = blockIdx.x * 64, p0 = blockIdx.y * 64, bz = blockIdx.z;
  const float* Bub = Bu + (size_t)bz * 256 * Ln;
  __hip_bfloat16* Xb = Xst + (size_t)bz * Ln * 256;
  const int t = threadIdx.x;
  const int tr = t >> 4, tc = t & 15;
#pragma unroll
  for (int i = 0; i < 4; i++) {
    float4 v = *(const float4*)&Bub[(size_t)(p0 + tr + 16 * i) * Ln + l0 + tc * 4];
    tile[tr + 16 * i][tc * 4 + 0] = v.x;
    tile[tr + 16 * i][tc * 4 + 1] = v.y;
    tile[tr + 16 * i][tc * 4 + 2] = v.z;
    tile[tr + 16 * i][tc * 4 + 3] = v.w;
  }
  __syncthreads();
#pragma unroll
  for (int i = 0; i < 4; i++) {
    int l = tr + 16 * i;
    short4v o;
    o.x = f2bf(tile[tc * 4 + 0][l]);
    o.y = f2bf(tile[tc * 4 + 1][l]);
    o.z = f2bf(tile[tc * 4 + 2][l]);
    o.w = f2bf(tile[tc * 4 + 3][l]);
    *(short4v*)&Xb[(size_t)(l0 + l) * 256 + p0 + tc * 4] = o;
  }
}

// ---------------------------------------------------------------- MFMA GEMM1
// Bu[bz][256][L] = Bmat[256][512] @ Ut[bz][L][512]^T   (both operands K-contig)
__global__ __launch_bounds__(256) void gemm1_kernel(
    const __hip_bfloat16* __restrict__ Amat,  // [256][512]
    const __hip_bfloat16* __restrict__ Ut,    // [NB][8192][512]
    float* __restrict__ Bu) {
  __shared__ __align__(16) short As[128 * 32];
  __shared__ __align__(16) short Bs[128 * 32];
  const int t = threadIdx.x;
  const int lane = t & 63, w = t >> 6;
  const int wm = w >> 1, wn = w & 1;
  const int n0 = blockIdx.x * 128;
  const int m0 = blockIdx.y * 128;
  const int bz = blockIdx.z;
  const __hip_bfloat16* Ub = Ut + (size_t)bz * Ln * Hn;

  const int srow = lane >> 2;          // 0..15
  const int scol = (lane & 3) * 16;    // byte col 0..48

  f32x4 acc[4][4] = {};
  for (int k0 = 0; k0 < Hn; k0 += 32) {
#pragma unroll
    for (int I2 = 0; I2 < 2; I2++) {
      int I = 2 * w + I2;
      int row = 16 * I + srow;
      async_copy16((const char*)(Amat + (size_t)(m0 + row) * Hn + k0) + scol,
                   (char*)As + I * 1024);
      async_copy16((const char*)(Ub + (size_t)(n0 + row) * Hn + k0) + scol,
                   (char*)Bs + I * 1024);
    }
    __syncthreads();
    bf16x8 af[4], bfr[4];
#pragma unroll
    for (int mt = 0; mt < 4; mt++)
      af[mt] = *(const bf16x8*)&As[(64 * wm + 16 * mt + (lane & 15)) * 32 + (lane >> 4) * 8];
#pragma unroll
    for (int nt = 0; nt < 4; nt++)
      bfr[nt] = *(const bf16x8*)&Bs[(64 * wn + 16 * nt + (lane & 15)) * 32 + (lane >> 4) * 8];
#pragma unroll
    for (int mt = 0; mt < 4; mt++)
#pragma unroll
      for (int nt = 0; nt < 4; nt++)
        acc[mt][nt] = __builtin_amdgcn_mfma_f32_16x16x32_bf16(
            af[mt], bfr[nt], acc[mt][nt], 0, 0, 0);
    __syncthreads();
  }
  const int row4 = (lane >> 4) * 4, col = lane & 15;
  float* Bub = Bu + (size_t)bz * 256 * Ln;
#pragma unroll
  for (int mt = 0; mt < 4; mt++)
#pragma unroll
    for (int nt = 0; nt < 4; nt++) {
      int n = n0 + 64 * wn + 16 * nt + col;
#pragma unroll
      for (int r = 0; r < 4; r++) {
        int m = m0 + 64 * wm + 16 * mt + row4 + r;
        Bub[(size_t)m * Ln + n] = acc[mt][nt][r];
      }
    }
}

// ---------------------------------------------------------------- scan
__global__ __launch_bounds__(256) void scan_kernel(float* __restrict__ Bu,
                                                   const float* __restrict__ Lam) {
  const int p = blockIdx.x;
  const int bz = blockIdx.y;
  const float Ar = Lam[p], Ai = Lam[Pn + p];
  float* rre = Bu + ((size_t)bz * 256 + p) * Ln;
  float* rim = Bu + ((size_t)bz * 256 + Pn + p) * Ln;
  const int t = threadIdx.x;
  const int l0 = t * 32;

  float br[32], bi[32];
  const float4* pr = (const float4*)(rre + l0);
  const float4* pi = (const float4*)(rim + l0);
#pragma unroll
  for (int i = 0; i < 8; i++) {
    float4 v = pr[i];
    br[4 * i] = v.x; br[4 * i + 1] = v.y; br[4 * i + 2] = v.z; br[4 * i + 3] = v.w;
  }
#pragma unroll
  for (int i = 0; i < 8; i++) {
    float4 v = pi[i];
    bi[4 * i] = v.x; bi[4 * i + 1] = v.y; bi[4 * i + 2] = v.z; bi[4 * i + 3] = v.w;
  }

  float xr = 0.f, xi = 0.f;
#pragma unroll
  for (int j = 0; j < 32; j++) {
    float nr = fmaf(Ar, xr, fmaf(-Ai, xi, br[j]));
    float ni = fmaf(Ar, xi, fmaf(Ai, xr, bi[j]));
    xr = nr; xi = ni;
  }
  float ar = Ar, ai = Ai;
#pragma unroll
  for (int s = 0; s < 5; s++) {
    float trr = ar * ar - ai * ai;
    float tii = 2.0f * ar * ai;
    ar = trr; ai = tii;
  }

  __shared__ float sar[256], sai[256], sbr[256], sbi[256];
  sar[t] = ar; sai[t] = ai; sbr[t] = xr; sbi[t] = xi;
  for (int off = 1; off < 256; off <<= 1) {
    __syncthreads();
    float par = 0.f, pai = 0.f, pbr = 0.f, pbi = 0.f;
    float car = 0.f, cai = 0.f, cbr = 0.f, cbi = 0.f;
    if (t >= off) {
      par = sar[t - off]; pai = sai[t - off];
      pbr = sbr[t - off]; pbi = sbi[t - off];
      car = sar[t]; cai = sai[t]; cbr = sbr[t]; cbi = sbi[t];
    }
    __syncthreads();
    if (t >= off) {
      sbr[t] = cbr + car * pbr - cai * pbi;
      sbi[t] = cbi + car * pbi + cai * pbr;
      sar[t] = car * par - cai * pai;
      sai[t] = car * pai + cai * par;
    }
  }
  __syncthreads();
  float cr = (t > 0) ? sbr[t - 1] : 0.f;
  float ci = (t > 0) ? sbi[t - 1] : 0.f;

  xr = cr; xi = ci;
  float4* qr = (float4*)(rre + l0);
  float4* qi = (float4*)(rim + l0);
#pragma unroll
  for (int i = 0; i < 8; i++) {
    float4 vr, vi;
#pragma unroll
    for (int c = 0; c < 4; c++) {
      float nr = fmaf(Ar, xr, fmaf(-Ai, xi, br[4 * i + c]));
      float ni = fmaf(Ar, xi, fmaf(Ai, xr, bi[4 * i + c]));
      xr = nr; xi = ni;
      (&vr.x)[c] = xr;
      (&vi.x)[c] = xi;
    }
    qr[i] = vr;
    qi[i] = vi;
  }
}

// ---------------------------------------------------------------- MFMA GEMM2
// Out[b][H][L] = gelu( Cmat[512][256] @ Xst[bz][L][256]^T + D[h]*U[b][h][l] )
__global__ __launch_bounds__(256) void gemm2_kernel(
    const __hip_bfloat16* __restrict__ Cmat,  // [512][256]
    const __hip_bfloat16* __restrict__ Xst,   // [NB][8192][256]
    const float* __restrict__ U,              // [8][512][8192]
    const float* __restrict__ Dv,             // [512]
    float* __restrict__ Out, int b0) {
  __shared__ __align__(16) short As[128 * 32];
  __shared__ __align__(16) short Bs[128 * 32];
  const int t = threadIdx.x;
  const int lane = t & 63, w = t >> 6;
  const int wm = w >> 1, wn = w & 1;
  const int n0 = blockIdx.x * 128;
  const int m0 = blockIdx.y * 128;
  const int bz = blockIdx.z;
  const int b = b0 + bz;
  const __hip_bfloat16* Xb = Xst + (size_t)bz * Ln * 256;

  const int srow = lane >> 2;
  const int scol = (lane & 3) * 16;

  f32x4 acc[4][4] = {};
  for (int k0 = 0; k0 < 256; k0 += 32) {
#pragma unroll
    for (int I2 = 0; I2 < 2; I2++) {
      int I = 2 * w + I2;
      int row = 16 * I + srow;
      async_copy16((const char*)(Cmat + (size_t)(m0 + row) * 256 + k0) + scol,
                   (char*)As + I * 1024);
      async_copy16((const char*)(Xb + (size_t)(n0 + row) * 256 + k0) + scol,
                   (char*)Bs + I * 1024);
    }
    __syncthreads();
    bf16x8 af[4], bfr[4];
#pragma unroll
    for (int mt = 0; mt < 4; mt++)
      af[mt] = *(const bf16x8*)&As[(64 * wm + 16 * mt + (lane & 15)) * 32 + (lane >> 4) * 8];
#pragma unroll
    for (int nt = 0; nt < 4; nt++)
      bfr[nt] = *(const bf16x8*)&Bs[(64 * wn + 16 * nt + (lane & 15)) * 32 + (lane >> 4) * 8];
#pragma unroll
    for (int mt = 0; mt < 4; mt++)
#pragma unroll
      for (int nt = 0; nt < 4; nt++)
        acc[mt][nt] = __builtin_amdgcn_mfma_f32_16x16x32_bf16(
            af[mt], bfr[nt], acc[mt][nt], 0, 0, 0);
    __syncthreads();
  }
  const int row4 = (lane >> 4) * 4, col = lane & 15;
#pragma unroll
  for (int mt = 0; mt < 4; mt++) {
#pragma unroll
    for (int r = 0; r < 4; r++) {
      int h = m0 + 64 * wm + 16 * mt + row4 + r;
      float dh = Dv[h];
      const float* Urow = U + ((size_t)b * Hn + h) * Ln;
      float* Orow = Out + ((size_t)b * Hn + h) * Ln;
#pragma unroll
      for (int nt = 0; nt < 4; nt++) {
        int n = n0 + 64 * wn + 16 * nt + col;
        float y = acc[mt][nt][r] + dh * Urow[n];
        Orow[n] = 0.5f * y * (1.0f + erff(y * 0.70710678118654752f));
      }
    }
  }
}

// ---------------------------------------------------------------- launch
extern "C" void kernel_launch(void* const* d_in, const int* in_sizes, int n_in,
                              void* d_out, int out_size, void* d_ws, size_t ws_size,
                              hipStream_t stream) {
  const float* U   = (const float*)d_in[0];
  const float* Lre = (const float*)d_in[1];
  const float* Lim = (const float*)d_in[2];
  const float* Bin = (const float*)d_in[3];
  const float* Cin = (const float*)d_in[4];
  const float* Dv  = (const float*)d_in[5];
  const float* ls  = (const float*)d_in[6];
  float* out = (float*)d_out;

  char* wsb = (char*)d_ws;
  float* Lam = (float*)wsb;
  __hip_bfloat16* Bmat = (__hip_bfloat16*)(wsb + 1024);
  __hip_bfloat16* Cmat = (__hip_bfloat16*)(wsb + 263168);

  // batch chunking if workspace is small (deterministic per session)
  int NB = 8;
  while (NB > 1 && ws_size < HEADB + (size_t)NB * (SZ_UT + SZ_BU + SZ_XS))
    NB >>= 1;
  char* big = wsb + HEADB;
  __hip_bfloat16* Ut  = (__hip_bfloat16*)big;
  float*          Bu  = (float*)(big + (size_t)NB * SZ_UT);
  __hip_bfloat16* Xst = (__hip_bfloat16*)(big + (size_t)NB * (SZ_UT + SZ_BU));

  precompute_kernel<<<(4 * Pn * Hn + 256 + 255) / 256, 256, 0, stream>>>(
      Lre, Lim, Bin, Cin, ls, Lam, Bmat, Cmat);

  for (int b0 = 0; b0 < BS; b0 += NB) {
    cvt_u_kernel<<<dim3(Ln / 64, Hn / 64, NB), 256, 0, stream>>>(U, Ut, b0);
    gemm1_kernel<<<dim3(Ln / 128, 2, NB), 256, 0, stream>>>(Bmat, Ut, Bu);
    scan_kernel<<<dim3(Pn, NB), 256, 0, stream>>>(Bu, Lam);
    cvt_xs_kernel<<<dim3(Ln / 64, 4, NB), 256, 0, stream>>>(Bu, Xst);
    gemm2_kernel<<<dim3(Ln / 128, Hn / 128, NB), 256, 0, stream>>>(
        Cmat, Xst, U, Dv, out, b0);
  }
}

// Round 3
// 356.165 us; speedup vs baseline: 2.0011x; 1.2982x over previous
//
#include <hip/hip_runtime.h>
#include <hip/hip_bf16.h>
#include <cmath>

namespace {
constexpr int Pn = 128;
constexpr int Hn = 512;
constexpr int Ln = 8192;
constexpr int BS = 8;
// ws byte layout:
//   [0,1024)              Lambda_bar fp32 (re[128] | im[128])
//   [1024, 263168)        Bmat bf16 [256][512]  (rows 0..127 re, 128..255 im)
//   [263168, 525312)      Cmat bf16 [512][256]  (+2*C_re | -2*C_im)
//   [525312, ...)         Bu fp32 [NB][256][8192]
constexpr size_t HEADB = 525312;
constexpr size_t SZ_BU = (size_t)256 * Ln * 4;     // 8388608 per batch
}

typedef __attribute__((ext_vector_type(4))) float f32x4;
typedef __attribute__((ext_vector_type(8))) short bf16x8;

static __device__ inline short f2bf(float x) {
  __hip_bfloat16 h = __float2bfloat16(x);
  return *(short*)&h;
}

static __device__ inline void async_copy16(const void* g, void* l) {
  __builtin_amdgcn_global_load_lds(
      (const __attribute__((address_space(1))) unsigned int*)g,
      (__attribute__((address_space(3))) unsigned int*)l, 16, 0, 0);
}

// ---------------------------------------------------------------- precompute
__global__ void precompute_kernel(const float* __restrict__ Lre,
                                  const float* __restrict__ Lim,
                                  const float* __restrict__ Bin,
                                  const float* __restrict__ Cin,
                                  const float* __restrict__ lstep,
                                  float* __restrict__ Lam,
                                  __hip_bfloat16* __restrict__ Bmat,
                                  __hip_bfloat16* __restrict__ Cmat) {
  int tid = blockIdx.x * blockDim.x + threadIdx.x;
  if (tid < 2 * Pn * Hn) {
    int r = tid >> 9;          // row in [0,256)
    int h = tid & (Hn - 1);
    int p = r & (Pn - 1);
    float st = expf(lstep[p]);
    float lr = Lre[p], li = Lim[p];
    float er = expf(lr * st);
    float cr = er * cosf(li * st);
    float ci = er * sinf(li * st);
    float nr = cr - 1.0f, ni = ci;
    float inv = 1.0f / (lr * lr + li * li);
    float wr = (nr * lr + ni * li) * inv;
    float wi = (ni * lr - nr * li) * inv;
    float btr = Bin[(p * Hn + h) * 2 + 0];
    float bti = Bin[(p * Hn + h) * 2 + 1];
    float val = (r < Pn) ? (wr * btr - wi * bti) : (wr * bti + wi * btr);
    Bmat[tid] = __float2bfloat16(val);
  } else if (tid < 4 * Pn * Hn) {
    int j = tid - 2 * Pn * Hn;
    int h = j >> 8;
    int c = j & 255;
    int p = c & (Pn - 1);
    float v = (c < Pn) ? 2.0f * Cin[(h * Pn + p) * 2 + 0]
                       : -2.0f * Cin[(h * Pn + p) * 2 + 1];
    Cmat[j] = __float2bfloat16(v);
  } else if (tid < 4 * Pn * Hn + 256) {
    int j = tid - 4 * Pn * Hn;
    int p = j & (Pn - 1);
    float st = expf(lstep[p]);
    float lr = Lre[p], li = Lim[p];
    float er = expf(lr * st);
    Lam[j] = (j < Pn) ? er * cosf(li * st) : er * sinf(li * st);
  }
}

// ---------------------------------------------------------------- MFMA GEMM1 (fused transpose+cast staging)
// Bu[bz][256][L] = Bmat[256][512] @ U[(b0+bz)][512][8192]
// A: bf16 K-contig, async global->LDS.  B: fp32 [k][n] -> bf16 LDS [n][k].
__global__ __launch_bounds__(256) void gemm1_kernel(
    const __hip_bfloat16* __restrict__ Amat,  // [256][512]
    const float* __restrict__ U,              // [8][512][8192]
    float* __restrict__ Bu,                   // [NB][256][8192]
    int b0) {
  __shared__ __align__(16) short As[128 * 32];
  __shared__ __align__(16) short Bs[128 * 40];   // stride 40 shorts (80 B, 16B-aligned)
  const int t = threadIdx.x;
  const int lane = t & 63, w = t >> 6;
  const int wm = w >> 1, wn = w & 1;
  const int n0 = blockIdx.x * 128;
  const int m0 = blockIdx.y * 128;
  const int bz = blockIdx.z;
  const float* Ub = U + (size_t)(b0 + bz) * Hn * Ln;

  const int srow = lane >> 2, scol = (lane & 3) * 16;
  const int bn = t & 127, bkg = t >> 7;   // staging: col n, k-group

  f32x4 acc[4][4] = {};
  for (int k0 = 0; k0 < Hn; k0 += 32) {
#pragma unroll
    for (int I2 = 0; I2 < 2; I2++) {
      int I = 2 * w + I2;
      async_copy16((const char*)(Amat + (size_t)(m0 + 16 * I + srow) * Hn + k0) + scol,
                   (char*)As + I * 1024);
    }
#pragma unroll
    for (int p = 0; p < 2; p++) {
      int kb = p * 16 + bkg * 8;
      float v[8];
#pragma unroll
      for (int j = 0; j < 8; j++)
        v[j] = Ub[(size_t)(k0 + kb + j) * Ln + n0 + bn];
      bf16x8 pk;
#pragma unroll
      for (int j = 0; j < 8; j++) pk[j] = f2bf(v[j]);
      *(bf16x8*)&Bs[bn * 40 + kb] = pk;
    }
    __syncthreads();
    bf16x8 af[4], bfr[4];
#pragma unroll
    for (int mt = 0; mt < 4; mt++)
      af[mt] = *(const bf16x8*)&As[(64 * wm + 16 * mt + (lane & 15)) * 32 + (lane >> 4) * 8];
#pragma unroll
    for (int nt = 0; nt < 4; nt++)
      bfr[nt] = *(const bf16x8*)&Bs[(64 * wn + 16 * nt + (lane & 15)) * 40 + (lane >> 4) * 8];
#pragma unroll
    for (int mt = 0; mt < 4; mt++)
#pragma unroll
      for (int nt = 0; nt < 4; nt++)
        acc[mt][nt] = __builtin_amdgcn_mfma_f32_16x16x32_bf16(
            af[mt], bfr[nt], acc[mt][nt], 0, 0, 0);
    __syncthreads();
  }
  const int row4 = (lane >> 4) * 4, col = lane & 15;
  float* Bub = Bu + (size_t)bz * 256 * Ln;
#pragma unroll
  for (int mt = 0; mt < 4; mt++)
#pragma unroll
    for (int nt = 0; nt < 4; nt++) {
      int n = n0 + 64 * wn + 16 * nt + col;
#pragma unroll
      for (int r = 0; r < 4; r++) {
        int m = m0 + 64 * wm + 16 * mt + row4 + r;
        Bub[(size_t)m * Ln + n] = acc[mt][nt][r];
      }
    }
}

// ---------------------------------------------------------------- scan
__global__ __launch_bounds__(256) void scan_kernel(float* __restrict__ Bu,
                                                   const float* __restrict__ Lam) {
  const int p = blockIdx.x;
  const int bz = blockIdx.y;
  const float Ar = Lam[p], Ai = Lam[Pn + p];
  float* rre = Bu + ((size_t)bz * 256 + p) * Ln;
  float* rim = Bu + ((size_t)bz * 256 + Pn + p) * Ln;
  const int t = threadIdx.x;
  const int l0 = t * 32;

  float br[32], bi[32];
  const float4* pr = (const float4*)(rre + l0);
  const float4* pi = (const float4*)(rim + l0);
#pragma unroll
  for (int i = 0; i < 8; i++) {
    float4 v = pr[i];
    br[4 * i] = v.x; br[4 * i + 1] = v.y; br[4 * i + 2] = v.z; br[4 * i + 3] = v.w;
  }
#pragma unroll
  for (int i = 0; i < 8; i++) {
    float4 v = pi[i];
    bi[4 * i] = v.x; bi[4 * i + 1] = v.y; bi[4 * i + 2] = v.z; bi[4 * i + 3] = v.w;
  }

  float xr = 0.f, xi = 0.f;
#pragma unroll
  for (int j = 0; j < 32; j++) {
    float nr = fmaf(Ar, xr, fmaf(-Ai, xi, br[j]));
    float ni = fmaf(Ar, xi, fmaf(Ai, xr, bi[j]));
    xr = nr; xi = ni;
  }
  float ar = Ar, ai = Ai;
#pragma unroll
  for (int s = 0; s < 5; s++) {
    float trr = ar * ar - ai * ai;
    float tii = 2.0f * ar * ai;
    ar = trr; ai = tii;
  }

  __shared__ float sar[256], sai[256], sbr[256], sbi[256];
  sar[t] = ar; sai[t] = ai; sbr[t] = xr; sbi[t] = xi;
  for (int off = 1; off < 256; off <<= 1) {
    __syncthreads();
    float par = 0.f, pai = 0.f, pbr = 0.f, pbi = 0.f;
    float car = 0.f, cai = 0.f, cbr = 0.f, cbi = 0.f;
    if (t >= off) {
      par = sar[t - off]; pai = sai[t - off];
      pbr = sbr[t - off]; pbi = sbi[t - off];
      car = sar[t]; cai = sai[t]; cbr = sbr[t]; cbi = sbi[t];
    }
    __syncthreads();
    if (t >= off) {
      sbr[t] = cbr + car * pbr - cai * pbi;
      sbi[t] = cbi + car * pbi + cai * pbr;
      sar[t] = car * par - cai * pai;
      sai[t] = car * pai + cai * par;
    }
  }
  __syncthreads();
  float cr = (t > 0) ? sbr[t - 1] : 0.f;
  float ci = (t > 0) ? sbi[t - 1] : 0.f;

  xr = cr; xi = ci;
  float4* qr = (float4*)(rre + l0);
  float4* qi = (float4*)(rim + l0);
#pragma unroll
  for (int i = 0; i < 8; i++) {
    float4 vr, vi;
#pragma unroll
    for (int c = 0; c < 4; c++) {
      float nr = fmaf(Ar, xr, fmaf(-Ai, xi, br[4 * i + c]));
      float ni = fmaf(Ar, xi, fmaf(Ai, xr, bi[4 * i + c]));
      xr = nr; xi = ni;
      (&vr.x)[c] = xr;
      (&vi.x)[c] = xi;
    }
    qr[i] = vr;
    qi[i] = vi;
  }
}

// ---------------------------------------------------------------- MFMA GEMM2 (fused transpose+cast staging + fast gelu)
// Out[b][H][L] = gelu( Cmat[512][256] @ Xs[bz][256][8192] + D[h]*U[b][h][l] )
__global__ __launch_bounds__(256) void gemm2_kernel(
    const __hip_bfloat16* __restrict__ Cmat,  // [512][256]
    const float* __restrict__ Xs,             // [NB][256][8192] fp32 (scan output)
    const float* __restrict__ U,              // [8][512][8192]
    const float* __restrict__ Dv,             // [512]
    float* __restrict__ Out, int b0) {
  __shared__ __align__(16) short As[128 * 32];
  __shared__ __align__(16) short Bs[128 * 40];
  const int t = threadIdx.x;
  const int lane = t & 63, w = t >> 6;
  const int wm = w >> 1, wn = w & 1;
  const int n0 = blockIdx.x * 128;
  const int m0 = blockIdx.y * 128;
  const int bz = blockIdx.z;
  const int b = b0 + bz;
  const float* Xb = Xs + (size_t)bz * 256 * Ln;

  const int srow = lane >> 2, scol = (lane & 3) * 16;
  const int bn = t & 127, bkg = t >> 7;

  f32x4 acc[4][4] = {};
  for (int k0 = 0; k0 < 256; k0 += 32) {
#pragma unroll
    for (int I2 = 0; I2 < 2; I2++) {
      int I = 2 * w + I2;
      async_copy16((const char*)(Cmat + (size_t)(m0 + 16 * I + srow) * 256 + k0) + scol,
                   (char*)As + I * 1024);
    }
#pragma unroll
    for (int p = 0; p < 2; p++) {
      int kb = p * 16 + bkg * 8;
      float v[8];
#pragma unroll
      for (int j = 0; j < 8; j++)
        v[j] = Xb[(size_t)(k0 + kb + j) * Ln + n0 + bn];
      bf16x8 pk;
#pragma unroll
      for (int j = 0; j < 8; j++) pk[j] = f2bf(v[j]);
      *(bf16x8*)&Bs[bn * 40 + kb] = pk;
    }
    __syncthreads();
    bf16x8 af[4], bfr[4];
#pragma unroll
    for (int mt = 0; mt < 4; mt++)
      af[mt] = *(const bf16x8*)&As[(64 * wm + 16 * mt + (lane & 15)) * 32 + (lane >> 4) * 8];
#pragma unroll
    for (int nt = 0; nt < 4; nt++)
      bfr[nt] = *(const bf16x8*)&Bs[(64 * wn + 16 * nt + (lane & 15)) * 40 + (lane >> 4) * 8];
#pragma unroll
    for (int mt = 0; mt < 4; mt++)
#pragma unroll
      for (int nt = 0; nt < 4; nt++)
        acc[mt][nt] = __builtin_amdgcn_mfma_f32_16x16x32_bf16(
            af[mt], bfr[nt], acc[mt][nt], 0, 0, 0);
    __syncthreads();
  }
  const int row4 = (lane >> 4) * 4, col = lane & 15;
#pragma unroll
  for (int mt = 0; mt < 4; mt++) {
#pragma unroll
    for (int r = 0; r < 4; r++) {
      int h = m0 + 64 * wm + 16 * mt + row4 + r;
      float dh = Dv[h];
      const float* Urow = U + ((size_t)b * Hn + h) * Ln;
      float* Orow = Out + ((size_t)b * Hn + h) * Ln;
#pragma unroll
      for (int nt = 0; nt < 4; nt++) {
        int n = n0 + 64 * wn + 16 * nt + col;
        float y = acc[mt][nt][r] + dh * Urow[n];
        // tanh-form gelu: y * sigmoid(2*0.7978845608*(y + 0.044715 y^3)), tail-safe
        float u2 = y * (0.7978845608f + 0.0356774081f * y * y);
        Orow[n] = y / (1.0f + __expf(-2.0f * u2));
      }
    }
  }
}

// ---------------------------------------------------------------- launch
extern "C" void kernel_launch(void* const* d_in, const int* in_sizes, int n_in,
                              void* d_out, int out_size, void* d_ws, size_t ws_size,
                              hipStream_t stream) {
  const float* U   = (const float*)d_in[0];
  const float* Lre = (const float*)d_in[1];
  const float* Lim = (const float*)d_in[2];
  const float* Bin = (const float*)d_in[3];
  const float* Cin = (const float*)d_in[4];
  const float* Dv  = (const float*)d_in[5];
  const float* ls  = (const float*)d_in[6];
  float* out = (float*)d_out;

  char* wsb = (char*)d_ws;
  float* Lam = (float*)wsb;
  __hip_bfloat16* Bmat = (__hip_bfloat16*)(wsb + 1024);
  __hip_bfloat16* Cmat = (__hip_bfloat16*)(wsb + 263168);

  int NB = 8;
  while (NB > 1 && ws_size < HEADB + (size_t)NB * SZ_BU)
    NB >>= 1;
  float* Bu = (float*)(wsb + HEADB);

  precompute_kernel<<<(4 * Pn * Hn + 256 + 255) / 256, 256, 0, stream>>>(
      Lre, Lim, Bin, Cin, ls, Lam, Bmat, Cmat);

  for (int b0 = 0; b0 < BS; b0 += NB) {
    gemm1_kernel<<<dim3(Ln / 128, 2, NB), 256, 0, stream>>>(Bmat, U, Bu, b0);
    scan_kernel<<<dim3(Pn, NB), 256, 0, stream>>>(Bu, Lam);
    gemm2_kernel<<<dim3(Ln / 128, Hn / 128, NB), 256, 0, stream>>>(
        Cmat, Bu, U, Dv, out, b0);
  }
}